// Round 4
// baseline (1575.851 us; speedup 1.0000x reference)
//
#include <hip/hip_runtime.h>

#define NN 320000
#define FF 128
#define EE 10240000
#define NBUCKET 1250        // NN/256 nodes per bucket
#define BCAP 8960           // per-bucket edge capacity (lambda=8192, ~1e-12 overflow)
#define EPB 40000           // edges per bucketing block (EE/256)

// ---------------- bucketing: pack edges by col-bucket ----------------
__global__ __launch_bounds__(1024) void k_bucket(const int* __restrict__ row,
                                                 const int* __restrict__ col,
                                                 int* __restrict__ gcur,
                                                 int* __restrict__ buf) {
  __shared__ int hist[NBUCKET];
  __shared__ int cur[NBUCKET];
  int t = threadIdx.x;
  int e0 = blockIdx.x * EPB;

  for (int b = t; b < NBUCKET; b += 1024) hist[b] = 0;
  __syncthreads();

  for (int i = t; i < EPB; i += 1024) {
    int c = col[e0 + i];
    atomicAdd(&hist[c >> 8], 1);
  }
  __syncthreads();

  for (int b = t; b < NBUCKET; b += 1024) {
    cur[b] = atomicAdd(&gcur[b], hist[b]);   // block's base within bucket b
  }
  __syncthreads();

  for (int i = t; i < EPB; i += 1024) {
    int e = e0 + i;
    int c = col[e];
    int r = row[e];
    int b = c >> 8;
    int slot = atomicAdd(&cur[b], 1);
    if (slot < BCAP) buf[b * BCAP + slot] = (r << 8) | (c & 255);
  }
}

// ---------------- per-bucket: counting-sort entries by row-slice (p>>23 = row>>15),
//                  compute degree -> dis, write sorted entries back ----------------
__global__ __launch_bounds__(256) void k_sortdeg(const int* __restrict__ gcur,
                                                 int* __restrict__ buf,
                                                 float* __restrict__ dis) {
  __shared__ int sbuf[BCAP];      // 35840 B
  __shared__ int hist[16];
  __shared__ int cur[16];
  __shared__ int degc[256];
  int t = threadIdx.x;
  int b = blockIdx.x;
  if (t < 16) { hist[t] = 0; }
  degc[t] = 0;
  __syncthreads();

  int cnt = gcur[b]; if (cnt > BCAP) cnt = BCAP;
  int* bb = buf + (long long)b * BCAP;

  for (int i = t; i < cnt; i += 256) {
    int p = bb[i];
    atomicAdd(&degc[p & 255], 1);
    atomicAdd(&hist[p >> 23], 1);     // slice = row >> 15, 10 slices
  }
  __syncthreads();
  if (t == 0) {
    int run = 0;
#pragma unroll
    for (int s = 0; s < 10; s++) { int v = hist[s]; cur[s] = run; run += v; }
  }
  __syncthreads();
  for (int i = t; i < cnt; i += 256) {
    int p = bb[i];
    int pos = atomicAdd(&cur[p >> 23], 1);
    sbuf[pos] = p;
  }
  __syncthreads();
  for (int i = t; i < cnt; i += 256) bb[i] = sbuf[i];
  dis[b * 256 + t] = rsqrtf((float)degc[t] + 2.0f);
}

// ---------------- fused: h0 = relu(xW_in+b_in); g1 = dis*(h0 W1); self = sl*(h0 W1)+b1 ----------------
__global__ __launch_bounds__(256) void k_h0(const float* __restrict__ x,
                                            const float* __restrict__ Win,
                                            const float* __restrict__ bin,
                                            const float* __restrict__ W1,
                                            const float* __restrict__ b1,
                                            const float* __restrict__ dis,
                                            float* __restrict__ g1,
                                            float* __restrict__ selfb) {
  int n = blockIdx.x * 256 + threadIdx.x;
  float acc[10];
#pragma unroll
  for (int l = 0; l < 10; l++) acc[l] = bin[l];

  const float4* xr = (const float4*)(x + (long long)n * FF);
#pragma unroll
  for (int j = 0; j < FF / 4; j++) {
    float4 v = xr[j];
    const float* w = Win + (j * 4) * 10;  // uniform -> s_load
#pragma unroll
    for (int l = 0; l < 10; l++) acc[l] = fmaf(v.x, w[l], acc[l]);
#pragma unroll
    for (int l = 0; l < 10; l++) acc[l] = fmaf(v.y, w[10 + l], acc[l]);
#pragma unroll
    for (int l = 0; l < 10; l++) acc[l] = fmaf(v.z, w[20 + l], acc[l]);
#pragma unroll
    for (int l = 0; l < 10; l++) acc[l] = fmaf(v.w, w[30 + l], acc[l]);
  }
  float h[10];
#pragma unroll
  for (int l = 0; l < 10; l++) h[l] = fmaxf(acc[l], 0.f);

  float hw[10];
#pragma unroll
  for (int l = 0; l < 10; l++) hw[l] = 0.f;
#pragma unroll
  for (int k = 0; k < 10; k++) {
    const float* wr = W1 + k * 10;
#pragma unroll
    for (int l = 0; l < 10; l++) hw[l] = fmaf(h[k], wr[l], hw[l]);
  }

  float di = dis[n];
  float sl = 2.0f * di * di;

  float4* gp = (float4*)(g1 + (long long)n * 12);
  gp[0] = make_float4(di * hw[0], di * hw[1], di * hw[2], di * hw[3]);
  gp[1] = make_float4(di * hw[4], di * hw[5], di * hw[6], di * hw[7]);
  gp[2] = make_float4(di * hw[8], di * hw[9], 0.f, 0.f);

  float2* sp = (float2*)(selfb + (long long)n * 10);
  sp[0] = make_float2(fmaf(sl, hw[0], b1[0]), fmaf(sl, hw[1], b1[1]));
  sp[1] = make_float2(fmaf(sl, hw[2], b1[2]), fmaf(sl, hw[3], b1[3]));
  sp[2] = make_float2(fmaf(sl, hw[4], b1[4]), fmaf(sl, hw[5], b1[5]));
  sp[3] = make_float2(fmaf(sl, hw[6], b1[6]), fmaf(sl, hw[7], b1[7]));
  sp[4] = make_float2(fmaf(sl, hw[8], b1[8]), fmaf(sl, hw[9], b1[9]));
}

__device__ __forceinline__ void acc_edge(float* __restrict__ su, int p,
                                         const float4 a, const float4 q, const float4 c) {
  float* s = su + (p & 255) * 13;
  atomicAdd(s + 0, a.x);
  atomicAdd(s + 1, a.y);
  atomicAdd(s + 2, a.z);
  atomicAdd(s + 3, a.w);
  atomicAdd(s + 4, q.x);
  atomicAdd(s + 5, q.y);
  atomicAdd(s + 6, q.z);
  atomicAdd(s + 7, q.w);
  atomicAdd(s + 8, c.x);
  atomicAdd(s + 9, c.y);
}

// ---------------- layer scatter via LDS accumulation (mid) ----------------
__global__ __launch_bounds__(256) void k_scatter_mid(const int* __restrict__ gcur,
                                                     const int* __restrict__ buf,
                                                     const float* __restrict__ g1,
                                                     const float* __restrict__ dis,
                                                     const float* __restrict__ W2,
                                                     const float* __restrict__ b2,
                                                     float* __restrict__ g2,
                                                     float* __restrict__ selfb) {
  __shared__ float su[256 * 13];
  int t = threadIdx.x;
  int b = blockIdx.x;
  for (int i = t; i < 256 * 13; i += 256) su[i] = 0.f;
  __syncthreads();

  int cnt = gcur[b]; if (cnt > BCAP) cnt = BCAP;
  const int* bb = buf + (long long)b * BCAP;

  int ng = cnt >> 10;           // groups of 1024 entries (256 threads x int4)
  for (int gi = 0; gi < ng; gi++) {
    int4 p4 = ((const int4*)bb)[gi * 256 + t];
    int pe[4] = {p4.x, p4.y, p4.z, p4.w};
    float4 A[4], Q[4], C[4];
#pragma unroll
    for (int k = 0; k < 4; k++) {
      const float4* gp = (const float4*)(g1 + (long long)(pe[k] >> 8) * 12);
      A[k] = gp[0]; Q[k] = gp[1]; C[k] = gp[2];
    }
#pragma unroll
    for (int k = 0; k < 4; k++) acc_edge(su, pe[k], A[k], Q[k], C[k]);
  }
  for (int i = (ng << 10) + t; i < cnt; i += 256) {
    int p = bb[i];
    const float4* gp = (const float4*)(g1 + (long long)(p >> 8) * 12);
    acc_edge(su, p, gp[0], gp[1], gp[2]);
  }
  __syncthreads();

  int n = b * 256 + t;
  float di = dis[n];
  float sl = 2.0f * di * di;
  const float* s = su + t * 13;
  const float2* sp = (const float2*)(selfb + (long long)n * 10);
  float2 s0 = sp[0], s1 = sp[1], s2 = sp[2], s3 = sp[3], s4 = sp[4];
  float h[10];
  h[0] = fmaxf(fmaf(di, s[0], s0.x), 0.f);
  h[1] = fmaxf(fmaf(di, s[1], s0.y), 0.f);
  h[2] = fmaxf(fmaf(di, s[2], s1.x), 0.f);
  h[3] = fmaxf(fmaf(di, s[3], s1.y), 0.f);
  h[4] = fmaxf(fmaf(di, s[4], s2.x), 0.f);
  h[5] = fmaxf(fmaf(di, s[5], s2.y), 0.f);
  h[6] = fmaxf(fmaf(di, s[6], s3.x), 0.f);
  h[7] = fmaxf(fmaf(di, s[7], s3.y), 0.f);
  h[8] = fmaxf(fmaf(di, s[8], s4.x), 0.f);
  h[9] = fmaxf(fmaf(di, s[9], s4.y), 0.f);

  float hw[10];
#pragma unroll
  for (int l = 0; l < 10; l++) hw[l] = 0.f;
#pragma unroll
  for (int k = 0; k < 10; k++) {
    const float* wr = W2 + k * 10;
#pragma unroll
    for (int l = 0; l < 10; l++) hw[l] = fmaf(h[k], wr[l], hw[l]);
  }

  float4* gp = (float4*)(g2 + (long long)n * 12);
  gp[0] = make_float4(di * hw[0], di * hw[1], di * hw[2], di * hw[3]);
  gp[1] = make_float4(di * hw[4], di * hw[5], di * hw[6], di * hw[7]);
  gp[2] = make_float4(di * hw[8], di * hw[9], 0.f, 0.f);

  float2* so = (float2*)(selfb + (long long)n * 10);
  so[0] = make_float2(fmaf(sl, hw[0], b2[0]), fmaf(sl, hw[1], b2[1]));
  so[1] = make_float2(fmaf(sl, hw[2], b2[2]), fmaf(sl, hw[3], b2[3]));
  so[2] = make_float2(fmaf(sl, hw[4], b2[4]), fmaf(sl, hw[5], b2[5]));
  so[3] = make_float2(fmaf(sl, hw[6], b2[6]), fmaf(sl, hw[7], b2[7]));
  so[4] = make_float2(fmaf(sl, hw[8], b2[8]), fmaf(sl, hw[9], b2[9]));
}

// ---------------- layer scatter (last) + output linear ----------------
__global__ __launch_bounds__(256) void k_scatter_out(const int* __restrict__ gcur,
                                                     const int* __restrict__ buf,
                                                     const float* __restrict__ g2,
                                                     const float* __restrict__ dis,
                                                     const float* __restrict__ selfb,
                                                     const float* __restrict__ Wout,
                                                     const float* __restrict__ bout,
                                                     float* __restrict__ out) {
  __shared__ float su[256 * 13];
  int t = threadIdx.x;
  int b = blockIdx.x;
  for (int i = t; i < 256 * 13; i += 256) su[i] = 0.f;
  __syncthreads();

  int cnt = gcur[b]; if (cnt > BCAP) cnt = BCAP;
  const int* bb = buf + (long long)b * BCAP;

  int ng = cnt >> 10;
  for (int gi = 0; gi < ng; gi++) {
    int4 p4 = ((const int4*)bb)[gi * 256 + t];
    int pe[4] = {p4.x, p4.y, p4.z, p4.w};
    float4 A[4], Q[4], C[4];
#pragma unroll
    for (int k = 0; k < 4; k++) {
      const float4* gp = (const float4*)(g2 + (long long)(pe[k] >> 8) * 12);
      A[k] = gp[0]; Q[k] = gp[1]; C[k] = gp[2];
    }
#pragma unroll
    for (int k = 0; k < 4; k++) acc_edge(su, pe[k], A[k], Q[k], C[k]);
  }
  for (int i = (ng << 10) + t; i < cnt; i += 256) {
    int p = bb[i];
    const float4* gp = (const float4*)(g2 + (long long)(p >> 8) * 12);
    acc_edge(su, p, gp[0], gp[1], gp[2]);
  }
  __syncthreads();

  int n = b * 256 + t;
  float di = dis[n];
  const float* s = su + t * 13;
  const float2* sp = (const float2*)(selfb + (long long)n * 10);
  float2 s0 = sp[0], s1 = sp[1], s2 = sp[2], s3 = sp[3], s4 = sp[4];
  float h[10];
  h[0] = fmaxf(fmaf(di, s[0], s0.x), 0.f);
  h[1] = fmaxf(fmaf(di, s[1], s0.y), 0.f);
  h[2] = fmaxf(fmaf(di, s[2], s1.x), 0.f);
  h[3] = fmaxf(fmaf(di, s[3], s1.y), 0.f);
  h[4] = fmaxf(fmaf(di, s[4], s2.x), 0.f);
  h[5] = fmaxf(fmaf(di, s[5], s2.y), 0.f);
  h[6] = fmaxf(fmaf(di, s[6], s3.x), 0.f);
  h[7] = fmaxf(fmaf(di, s[7], s3.y), 0.f);
  h[8] = fmaxf(fmaf(di, s[8], s4.x), 0.f);
  h[9] = fmaxf(fmaf(di, s[9], s4.y), 0.f);
  float o = bout[0];
#pragma unroll
  for (int l = 0; l < 10; l++) o = fmaf(h[l], Wout[l], o);
  out[n] = o;
}

extern "C" void kernel_launch(void* const* d_in, const int* in_sizes, int n_in,
                              void* d_out, int out_size, void* d_ws, size_t ws_size,
                              hipStream_t stream) {
  const float* x    = (const float*)d_in[0];
  const int*   ei   = (const int*)d_in[1];
  const float* Win  = (const float*)d_in[2];
  const float* bin  = (const float*)d_in[3];
  const float* W1   = (const float*)d_in[4];
  const float* b1   = (const float*)d_in[5];
  const float* W2   = (const float*)d_in[6];
  const float* b2   = (const float*)d_in[7];
  const float* Wout = (const float*)d_in[8];
  const float* bout = (const float*)d_in[9];
  float* out = (float*)d_out;

  // workspace: buf[1250*8960] | gcur[2048] | dis[N] | g1[12N] | g2[12N] | self[10N]
  int*   buf   = (int*)d_ws;
  int*   gcur  = buf + (long long)NBUCKET * BCAP;
  float* dis   = (float*)(gcur + 2048);
  float* g1    = dis + NN;
  float* g2    = g1 + 12 * NN;
  float* selfb = g2 + 12 * NN;

  const int* row = ei;        // edge_index[0]
  const int* col = ei + EE;   // edge_index[1]

  hipMemsetAsync(gcur, 0, NBUCKET * sizeof(int), stream);
  k_bucket<<<256, 1024, 0, stream>>>(row, col, gcur, buf);
  k_sortdeg<<<NBUCKET, 256, 0, stream>>>(gcur, buf, dis);
  k_h0<<<NN / 256, 256, 0, stream>>>(x, Win, bin, W1, b1, dis, g1, selfb);
  k_scatter_mid<<<NBUCKET, 256, 0, stream>>>(gcur, buf, g1, dis, W2, b2, g2, selfb);
  k_scatter_out<<<NBUCKET, 256, 0, stream>>>(gcur, buf, g2, dis, selfb, Wout, bout, out);
}